// Round 1
// baseline (765.722 us; speedup 1.0000x reference)
//
#include <hip/hip_runtime.h>
#include <hip/hip_bf16.h>
#include <stdint.h>

typedef __bf16 bf16x8 __attribute__((ext_vector_type(8)));
typedef float  f32x4  __attribute__((ext_vector_type(4)));

__device__ __forceinline__ void gload_lds16(const void* g, void* l) {
  __builtin_amdgcn_global_load_lds(
      (const __attribute__((address_space(1))) void*)g,
      (__attribute__((address_space(3))) void*)l, 16, 0, 0);
}

// ---------------- RMSNorm: fp32 row (H=2048) -> bf16 row ----------------
__global__ __launch_bounds__(256) void rmsnorm_kernel(
    const float* __restrict__ x, const float* __restrict__ w,
    __bf16* __restrict__ out) {
  constexpr int H = 2048;
  const int row = blockIdx.x;
  const int t = threadIdx.x;
  const float4* xr = (const float4*)(x + (size_t)row * H);
  float4 a = xr[t * 2 + 0];
  float4 b = xr[t * 2 + 1];
  float ss = a.x*a.x + a.y*a.y + a.z*a.z + a.w*a.w
           + b.x*b.x + b.y*b.y + b.z*b.z + b.w*b.w;
#pragma unroll
  for (int o = 32; o > 0; o >>= 1) ss += __shfl_xor(ss, o);
  __shared__ float red[4];
  if ((t & 63) == 0) red[t >> 6] = ss;
  __syncthreads();
  float tot = red[0] + red[1] + red[2] + red[3];
  float r = rsqrtf(tot * (1.0f / H) + 1e-6f);
  const float4* wr4 = (const float4*)w;
  float4 wa = wr4[t * 2 + 0];
  float4 wb = wr4[t * 2 + 1];
  bf16x8 ov;
  ov[0] = (__bf16)(a.x * wa.x * r);
  ov[1] = (__bf16)(a.y * wa.y * r);
  ov[2] = (__bf16)(a.z * wa.z * r);
  ov[3] = (__bf16)(a.w * wa.w * r);
  ov[4] = (__bf16)(b.x * wb.x * r);
  ov[5] = (__bf16)(b.y * wb.y * r);
  ov[6] = (__bf16)(b.z * wb.z * r);
  ov[7] = (__bf16)(b.w * wb.w * r);
  *(bf16x8*)(out + (size_t)row * H + (size_t)t * 8) = ov;
}

// ---------------- AWQ dequant -> transposed bf16 weight (N x K) ----------------
// qw: [K][Cp] int32 packed (8 x 4-bit along N, shift order 0,4,1,5,2,6,3,7 nibbles)
// qz: [K/128][Cp], sc: [K/128][Nfull]
// Output wt: [Nout][K] where Nout = 8 * (gridDim.y * 64) (always a prefix of columns)
__global__ __launch_bounds__(256) void dequant_t_kernel(
    const int* __restrict__ qw, const int* __restrict__ qz,
    const float* __restrict__ sc, __bf16* __restrict__ wt,
    int K, int Cp, int Nfull) {
  const int t = threadIdx.x;
  const int k = blockIdx.x * 64 + (t & 63);
  const int c0 = blockIdx.y * 64 + (t >> 6) * 16;
  const int g = k >> 7;  // GROUP_SIZE = 128
  const uint32_t* qwr = (const uint32_t*)qw + (size_t)k * Cp + c0;
  const uint32_t* qzr = (const uint32_t*)qz + (size_t)g * Cp + c0;
  const float* scr = sc + (size_t)g * Nfull + (size_t)c0 * 8;

  uint32_t u[16], z[16];
  *(int4*)(&u[0])  = *(const int4*)(qwr + 0);
  *(int4*)(&u[4])  = *(const int4*)(qwr + 4);
  *(int4*)(&u[8])  = *(const int4*)(qwr + 8);
  *(int4*)(&u[12]) = *(const int4*)(qwr + 12);
  *(int4*)(&z[0])  = *(const int4*)(qzr + 0);
  *(int4*)(&z[4])  = *(const int4*)(qzr + 4);
  *(int4*)(&z[8])  = *(const int4*)(qzr + 8);
  *(int4*)(&z[12]) = *(const int4*)(qzr + 12);

#pragma unroll
  for (int i = 0; i < 16; i++) {
    const uint32_t uu = u[i], zz = z[i];
#pragma unroll
    for (int s = 0; s < 8; s++) {
      const int sh = ((s >> 1) * 4) + ((s & 1) ? 16 : 0);  // {0,16,4,20,8,24,12,28}
      float wv = ((float)((uu >> sh) & 15u) - (float)((zz >> sh) & 15u)) * scr[i * 8 + s];
      wt[((size_t)(c0 + i) * 8 + s) * (size_t)K + k] = (__bf16)wv;
    }
  }
}

// ---------------- bf16 GEMM, B given transposed (N x K), 128x128 tile ----------------
// EPI 0: C (bf16) = A @ B^T      EPI 1: C (f32) = addend + A @ B^T
template <int EPI>
__global__ __launch_bounds__(256) void gemm_bt_kernel(
    const __bf16* __restrict__ A,   // [M][K]
    const __bf16* __restrict__ Bt,  // [N][K]
    void* __restrict__ Cv,
    const float* __restrict__ addend,
    int M, int N, int K) {
  __shared__ __bf16 Alds[128 * 64];
  __shared__ __bf16 Blds[128 * 64];

  const int t = threadIdx.x;
  const int l = t & 63;
  const int w = t >> 6;
  const int wr = w >> 1, wc = w & 1;
  const int lm = l & 15, kb = l >> 4;
  const int bn0 = blockIdx.x * 128;
  const int bm0 = blockIdx.y * 128;

  f32x4 acc[4][4] = {};

  const __bf16* Ab = A + (size_t)bm0 * K;
  const __bf16* Bb = Bt + (size_t)bn0 * K;

  for (int kt = 0; kt < K; kt += 64) {
#pragma unroll
    for (int r = 0; r < 4; r++) {
      const int slot = r * 256 + t;          // lds 16B-slot index == global (row,seg)
      const int row = slot >> 3, seg = slot & 7;
      const __bf16* asrc = Ab + (size_t)row * K + kt + seg * 8;
      const __bf16* bsrc = Bb + (size_t)row * K + kt + seg * 8;
      __bf16* adst = &Alds[(size_t)(r * 256 + w * 64) * 8];  // wave-uniform base
      __bf16* bdst = &Blds[(size_t)(r * 256 + w * 64) * 8];
      gload_lds16(asrc, adst);
      gload_lds16(bsrc, bdst);
    }
    __syncthreads();
#pragma unroll
    for (int kk = 0; kk < 2; kk++) {
      bf16x8 af[4], bfv[4];
#pragma unroll
      for (int mi = 0; mi < 4; mi++)
        af[mi] = *(const bf16x8*)&Alds[(wr * 64 + mi * 16 + lm) * 64 + kk * 32 + kb * 8];
#pragma unroll
      for (int ni = 0; ni < 4; ni++)
        bfv[ni] = *(const bf16x8*)&Blds[(wc * 64 + ni * 16 + lm) * 64 + kk * 32 + kb * 8];
#pragma unroll
      for (int mi = 0; mi < 4; mi++)
#pragma unroll
        for (int ni = 0; ni < 4; ni++)
          acc[mi][ni] = __builtin_amdgcn_mfma_f32_16x16x32_bf16(af[mi], bfv[ni], acc[mi][ni], 0, 0, 0);
    }
    __syncthreads();
  }

#pragma unroll
  for (int mi = 0; mi < 4; mi++) {
#pragma unroll
    for (int ni = 0; ni < 4; ni++) {
      const int col = bn0 + wc * 64 + ni * 16 + lm;
#pragma unroll
      for (int r = 0; r < 4; r++) {
        const int row = bm0 + wr * 64 + mi * 16 + kb * 4 + r;
        const size_t idx = (size_t)row * N + col;
        if (EPI == 0)
          ((__bf16*)Cv)[idx] = (__bf16)acc[mi][ni][r];
        else
          ((float*)Cv)[idx] = addend[idx] + acc[mi][ni][r];
      }
    }
  }
}

// ---------------- silu(gate) * up ----------------
__global__ __launch_bounds__(256) void silu_mul_kernel(
    const __bf16* __restrict__ gu, __bf16* __restrict__ act) {
  const size_t tid = (size_t)blockIdx.x * 256 + threadIdx.x;
  const size_t row = tid >> 10;          // I/8 = 1024 chunks per row
  const size_t c8 = (tid & 1023) * 8;
  const bf16x8 g = *(const bf16x8*)&gu[row * 16384 + c8];
  const bf16x8 u = *(const bf16x8*)&gu[row * 16384 + 8192 + c8];
  bf16x8 o;
#pragma unroll
  for (int j = 0; j < 8; j++) {
    float gf = (float)g[j], uf = (float)u[j];
    o[j] = (__bf16)(uf * (gf / (1.0f + __expf(-gf))));
  }
  *(bf16x8*)&act[row * 8192 + c8] = o;
}

extern "C" void kernel_launch(void* const* d_in, const int* in_sizes, int n_in,
                              void* d_out, int out_size, void* d_ws, size_t ws_size,
                              hipStream_t stream) {
  const float* x      = (const float*)d_in[0];
  const float* ln1    = (const float*)d_in[1];
  const float* ln2    = (const float*)d_in[2];
  const int*   qkv_qw = (const int*)d_in[3];
  const int*   qkv_qz = (const int*)d_in[4];
  const float* qkv_sc = (const float*)d_in[5];
  const int*   o_qw   = (const int*)d_in[6];
  const int*   o_qz   = (const int*)d_in[7];
  const float* o_sc   = (const float*)d_in[8];
  const int*   gu_qw  = (const int*)d_in[9];
  const int*   gu_qz  = (const int*)d_in[10];
  const float* gu_sc  = (const float*)d_in[11];
  const int*   dn_qw  = (const int*)d_in[12];
  const int*   dn_qz  = (const int*)d_in[13];
  const float* dn_sc  = (const float*)d_in[14];

  constexpr int H = 2048, I = 8192, M = 4096;

  // Workspace layout (268,435,456 bytes total, with region reuse):
  char* ws = (char*)d_ws;
  __bf16* h   = (__bf16*)(ws + 0);                 // 16 MiB  [4096][2048] bf16
  __bf16* q   = (__bf16*)(ws + 16777216ULL);       // 16 MiB  [4096][2048] bf16
  float*  x2  = (float*)(ws + 33554432ULL);        // 32 MiB  [4096][2048] f32
  __bf16* W   = (__bf16*)(ws + 67108864ULL);       // 64 MiB  weight^T region (reused)
  __bf16* act = W;                                 // 64 MiB  [4096][8192] bf16 (after Wgu dead)
  __bf16* gu  = (__bf16*)(ws + 134217728ULL);      // 128 MiB [4096][16384] bf16
  __bf16* Wdn = (__bf16*)(ws + 0);                 // 32 MiB  [2048][8192] bf16 (h,q dead)

  // 1. h1 = rmsnorm(x, ln1)
  rmsnorm_kernel<<<dim3(M), dim3(256), 0, stream>>>(x, ln1, h);
  // 2. Wq^T (only first 2048 output cols of qkv — k/v are unused by the reference)
  dequant_t_kernel<<<dim3(H / 64, 4), dim3(256), 0, stream>>>(qkv_qw, qkv_qz, qkv_sc, W, H, 768, 6144);
  // 3. q = h1 @ Wq
  gemm_bt_kernel<0><<<dim3(H / 128, M / 128), dim3(256), 0, stream>>>(h, W, (void*)q, nullptr, M, H, H);
  // 4. Wo^T
  dequant_t_kernel<<<dim3(H / 64, 4), dim3(256), 0, stream>>>(o_qw, o_qz, o_sc, W, H, 256, 2048);
  // 5. x2 = x + q @ Wo
  gemm_bt_kernel<1><<<dim3(H / 128, M / 128), dim3(256), 0, stream>>>(q, W, (void*)x2, x, M, H, H);
  // 6. h2 = rmsnorm(x2, ln2)
  rmsnorm_kernel<<<dim3(M), dim3(256), 0, stream>>>(x2, ln2, h);
  // 7. Wgu^T  [16384][2048]
  dequant_t_kernel<<<dim3(H / 64, 32), dim3(256), 0, stream>>>(gu_qw, gu_qz, gu_sc, W, H, 2048, 16384);
  // 8. gate_up = h2 @ Wgu
  gemm_bt_kernel<0><<<dim3(2 * I / 128, M / 128), dim3(256), 0, stream>>>(h, W, (void*)gu, nullptr, M, 2 * I, H);
  // 9. act = silu(gate) * up   (act overwrites the dead Wgu region)
  silu_mul_kernel<<<dim3(M * (I / 8) / 256), dim3(256), 0, stream>>>(gu, act);
  // 10. Wdn^T [2048][8192] into dead h+q region
  dequant_t_kernel<<<dim3(I / 64, 4), dim3(256), 0, stream>>>(dn_qw, dn_qz, dn_sc, Wdn, I, 256, 2048);
  // 11. out = x2 + act @ Wdn
  gemm_bt_kernel<1><<<dim3(H / 128, M / 128), dim3(256), 0, stream>>>(act, Wdn, d_out, x2, M, H, I);
}